// Round 1
// baseline (449.162 us; speedup 1.0000x reference)
//
#include <hip/hip_runtime.h>
#include <hip/hip_bf16.h>
#include <stdint.h>

// ---------------------------------------------------------------------------
// GSVD layer: y = x @ (U diag(S) Vh)^T, factored as
//   t = x @ (S*Vh)^T   [M=8192, R=1024],  K=4096
//   y = t @ U^T        [M=8192, O=4096],  K=1024
// bf16 MFMA 16x16x32, fp32 accumulate.
// GEMM: 256x256 tile, BK=64, 8 waves (2Mx4N), 8-phase schedule with counted
// vmcnt (T3+T4), st_16x32 LDS swizzle (T2), setprio around MFMA (T5).
// ---------------------------------------------------------------------------

typedef __attribute__((ext_vector_type(8))) __bf16 bf16x8;
typedef __attribute__((ext_vector_type(4))) float f32x4;

#define AS1(p) ((const __attribute__((address_space(1))) void*)(p))
#define AS3(p) ((__attribute__((address_space(3))) void*)(p))

static __device__ __forceinline__ unsigned short f2bf(float f) {
  union { float f; unsigned int u; } c; c.f = f;
  unsigned int u = c.u;
  return (unsigned short)((u + 0x7FFFu + ((u >> 16) & 1u)) >> 16);
}

// fp32 -> bf16 cast, 4 elems/thread
__global__ void cast_bf16_k(const float* __restrict__ in,
                            unsigned short* __restrict__ out, int n4) {
  int gid = blockIdx.x * blockDim.x + threadIdx.x;
  if (gid >= n4) return;
  const float4 v = ((const float4*)in)[gid];
  ushort4 o;
  o.x = f2bf(v.x); o.y = f2bf(v.y); o.z = f2bf(v.z); o.w = f2bf(v.w);
  ((ushort4*)out)[gid] = o;
}

// Vs[r][i] = bf16(S[r] * Vh[r][i])
__global__ void scale_cast_k(const float* __restrict__ Vh,
                             const float* __restrict__ S,
                             unsigned short* __restrict__ out,
                             int n4, int din4) {
  int gid = blockIdx.x * blockDim.x + threadIdx.x;
  if (gid >= n4) return;
  float s = S[gid / din4];
  const float4 v = ((const float4*)Vh)[gid];
  ushort4 o;
  o.x = f2bf(v.x * s); o.y = f2bf(v.y * s);
  o.z = f2bf(v.z * s); o.w = f2bf(v.w * s);
  ((ushort4*)out)[gid] = o;
}

// ---------------------------------------------------------------------------
// C[m,n] = sum_k A[m,k]*B[n,k]  (A:[M,K], B:[N,K], both bf16 row-major)
// 256x256 tile, BK=64, 512 threads = 8 waves in 2Mx4N, per-wave 128x64 out.
// LDS: 8 regions x 16KB = 128KB: [dbuf(2)][op A/B][half(2)][128 rows x 64 k].
// Swizzle: physical LDS byte = logical ^ (((logical>>9)&1)<<5)  (st_16x32).
// Staging: linear global_load_lds dest + inverse-swizzled global source.
// 8-phase schedule per 2 K-tiles; vmcnt(4) only at ph3/ph7.
// Requires M%256==0, N%256==0, K%128==0 (shapes here: yes).
// ---------------------------------------------------------------------------

#define BAR() __builtin_amdgcn_s_barrier()
#define WAITLG0() asm volatile("s_waitcnt lgkmcnt(0)" ::: "memory")
#define WAITLG8() asm volatile("s_waitcnt lgkmcnt(8)" ::: "memory")
#define WAITVM4() asm volatile("s_waitcnt vmcnt(4)" ::: "memory")

template <bool OUT_BF16>
__global__ __launch_bounds__(512)
void gemm256(const __bf16* __restrict__ A, const __bf16* __restrict__ B,
             void* __restrict__ C, int N, int K) {
  __shared__ __bf16 sm[8][8192];  // region = dbuf*4 + op*2 + half, 16KB each

  const int t    = threadIdx.x;
  const int lane = t & 63;
  const int wid  = __builtin_amdgcn_readfirstlane(t >> 6);
  const int q    = lane >> 4;   // k-group within MFMA fragment
  const int lr   = lane & 15;   // row/col within 16x16 fragment

  const int bm = blockIdx.x, bn = blockIdx.y;
  const int wmh = wid >> 2;          // which A half this wave consumes
  const int wn4 = wid & 3;
  const int bh  = wn4 >> 1;          // which B half this wave consumes
  const int wnr = (wn4 & 1) * 64;    // row base inside B half

  // swizzled k-byte offsets for ds_read: row bit2 (== (lr>>2)&1) flips bit5
  const int kx  = ((lr >> 2) & 1) << 5;
  const int ko0 = (q * 16) ^ kx;        // k-half 0
  const int ko1 = (64 + q * 16) ^ kx;   // k-half 1

  const size_t halfK = (size_t)128 * K;

  // staging source pointers: lane's 16B chunk, inverse-swizzled
  const __bf16* pA[2]; const __bf16* pB[2];
#pragma unroll
  for (int li = 0; li < 2; ++li) {
    const int phys = li * 8192 + wid * 1024 + lane * 16;  // linear LDS byte
    const int lg   = phys ^ (((phys >> 9) & 1) << 5);     // logical byte
    const int grow = lg >> 7, gkb = lg & 127;
    pA[li] = A + (size_t)(bm * 256 + grow) * K + (gkb >> 1);
    pB[li] = B + (size_t)(bn * 256 + grow) * K + (gkb >> 1);
  }

#define STAGE(P, reg, h, tt)                                                   \
  {                                                                            \
    __bf16* l_ = &sm[(reg)][0] + wid * 512;                                    \
    __builtin_amdgcn_global_load_lds(AS1(P[0] + (h) * halfK + (size_t)(tt) * 64), \
                                     AS3(l_), 16, 0, 0);                       \
    __builtin_amdgcn_global_load_lds(AS1(P[1] + (h) * halfK + (size_t)(tt) * 64), \
                                     AS3(l_ + 4096), 16, 0, 0);                \
  }

#define LDA(d, mf, kh) \
  (*(const bf16x8*)((const char*)&sm[(d) * 4 + wmh][0] + ((mf) * 16 + lr) * 128 + ko##kh))
#define LDB(d, nf, kh) \
  (*(const bf16x8*)((const char*)&sm[(d) * 4 + 2 + bh][0] + (wnr + (nf) * 16 + lr) * 128 + ko##kh))

#define READ_A(d, mh, dst)                                                    \
  dst[0][0] = LDA(d, (mh) * 4 + 0, 0); dst[0][1] = LDA(d, (mh) * 4 + 0, 1);   \
  dst[1][0] = LDA(d, (mh) * 4 + 1, 0); dst[1][1] = LDA(d, (mh) * 4 + 1, 1);   \
  dst[2][0] = LDA(d, (mh) * 4 + 2, 0); dst[2][1] = LDA(d, (mh) * 4 + 2, 1);   \
  dst[3][0] = LDA(d, (mh) * 4 + 3, 0); dst[3][1] = LDA(d, (mh) * 4 + 3, 1);

#define READ_B(d, nh, dst)                                                    \
  dst[0][0] = LDB(d, (nh) * 2 + 0, 0); dst[0][1] = LDB(d, (nh) * 2 + 0, 1);   \
  dst[1][0] = LDB(d, (nh) * 2 + 1, 0); dst[1][1] = LDB(d, (nh) * 2 + 1, 1);

#define MFMA_Q(mh, nh, ar, br)                                                \
  __builtin_amdgcn_s_setprio(1);                                              \
  _Pragma("unroll") for (int mi = 0; mi < 4; ++mi) {                          \
    _Pragma("unroll") for (int ni = 0; ni < 2; ++ni) {                        \
      acc[(mh) * 4 + mi][(nh) * 2 + ni] =                                     \
          __builtin_amdgcn_mfma_f32_16x16x32_bf16(                            \
              ar[mi][0], br[ni][0], acc[(mh) * 4 + mi][(nh) * 2 + ni], 0, 0, 0); \
      acc[(mh) * 4 + mi][(nh) * 2 + ni] =                                     \
          __builtin_amdgcn_mfma_f32_16x16x32_bf16(                            \
              ar[mi][1], br[ni][1], acc[(mh) * 4 + mi][(nh) * 2 + ni], 0, 0, 0); \
    }                                                                         \
  }                                                                           \
  __builtin_amdgcn_s_setprio(0);

  f32x4 acc[8][4] = {};
  bf16x8 aA[4][2], aB[4][2], bA[2][2], bB[2][2];

  const int NT = K >> 6;  // K-tiles of 64

  // prologue: tile0 -> dbuf0 {A0,A1,B0,B1}; tile1 -> dbuf1 {A0,A1}
  STAGE(pA, 0, 0, 0); STAGE(pA, 1, 1, 0);
  STAGE(pB, 2, 0, 0); STAGE(pB, 3, 1, 0);
  STAGE(pA, 4, 0, 1); STAGE(pA, 5, 1, 1);
  WAITVM4();  // tile0 fully landed; tile1 A-halves still in flight
  BAR();

  for (int i = 0; i < NT / 2; ++i) {
    const int t1 = 2 * i + 1;
    const int t2 = (2 * i + 2 < NT) ? 2 * i + 2 : NT - 1;  // clamped: tail
    const int t3 = (2 * i + 3 < NT) ? 2 * i + 3 : NT - 1;  // stages unread

    // ---- K-tile 2i from dbuf0 ----
    // ph0: read A-mh0 + B-nh0 (12 ds_reads); stage dbuf1.B0 <- t1
    READ_A(0, 0, aA);
    READ_B(0, 0, bA);
    STAGE(pB, 6, 0, t1);
    WAITLG8();
    BAR(); WAITLG0();
    MFMA_Q(0, 0, aA, bA);
    BAR();
    // ph1: read A-mh1; stage dbuf1.B1 <- t1
    READ_A(0, 1, aB);
    STAGE(pB, 7, 1, t1);
    BAR(); WAITLG0();
    MFMA_Q(1, 0, aB, bA);
    BAR();
    // ph2: read B-nh1; stage dbuf0.A0 <- t2 (dbuf0.A reads done at ph1)
    READ_B(0, 1, bB);
    STAGE(pA, 0, 0, t2);
    BAR(); WAITLG0();
    MFMA_Q(0, 1, aA, bB);
    BAR();
    // ph3: stage dbuf0.A1 <- t2; vmcnt(4) => t1 fully landed for ph4..7
    STAGE(pA, 1, 1, t2);
    WAITVM4();
    BAR();
    MFMA_Q(1, 1, aB, bB);
    BAR();

    // ---- K-tile 2i+1 from dbuf1 ----
    // ph4: stage dbuf0.B0 <- t2 (dbuf0.B reads done at ph2)
    READ_A(1, 0, aA);
    READ_B(1, 0, bA);
    STAGE(pB, 2, 0, t2);
    WAITLG8();
    BAR(); WAITLG0();
    MFMA_Q(0, 0, aA, bA);
    BAR();
    // ph5: stage dbuf0.B1 <- t2
    READ_A(1, 1, aB);
    STAGE(pB, 3, 1, t2);
    BAR(); WAITLG0();
    MFMA_Q(1, 0, aB, bA);
    BAR();
    // ph6: stage dbuf1.A0 <- t3 (dbuf1.A reads done at ph5)
    READ_B(1, 1, bB);
    STAGE(pA, 4, 0, t3);
    BAR(); WAITLG0();
    MFMA_Q(0, 1, aA, bB);
    BAR();
    // ph7: stage dbuf1.A1 <- t3; vmcnt(4) => t2 fully landed for next ph0..3
    STAGE(pA, 5, 1, t3);
    WAITVM4();
    BAR();
    MFMA_Q(1, 1, aB, bB);
    BAR();
  }

  // epilogue: C/D layout col=lane&15, row=(lane>>4)*4+reg  [m89/m91 verified]
  const int wm = wmh * 128;
  const int wn = wn4 * 64;
  const int r0 = q * 4;
#pragma unroll
  for (int mf = 0; mf < 8; ++mf) {
#pragma unroll
    for (int nf = 0; nf < 4; ++nf) {
      const int col = bn * 256 + wn + nf * 16 + lr;
      const size_t rb = (size_t)(bm * 256 + wm + mf * 16 + r0);
#pragma unroll
      for (int r = 0; r < 4; ++r) {
        const float v = acc[mf][nf][r];
        if (OUT_BF16) ((unsigned short*)C)[(rb + r) * N + col] = f2bf(v);
        else          ((float*)C)[(rb + r) * N + col] = v;
      }
    }
  }
}

extern "C" void kernel_launch(void* const* d_in, const int* in_sizes, int n_in,
                              void* d_out, int out_size, void* d_ws, size_t ws_size,
                              hipStream_t stream) {
  const float* x  = (const float*)d_in[0];  // [4,2048,4096] = [8192,4096]
  const float* U  = (const float*)d_in[1];  // [4096,1024]
  const float* S  = (const float*)d_in[2];  // [1024]
  const float* Vh = (const float*)d_in[3];  // [1024,4096]
  float* y = (float*)d_out;                 // [8192,4096] fp32

  const int M = 8192, DIN = 4096, DOUT = 4096, R = 1024;

  char* ws = (char*)d_ws;
  unsigned short* xb = (unsigned short*)(ws);              // 67108864 B  x  bf16
  unsigned short* vs = (unsigned short*)(ws + 67108864);   //  8388608 B  S*Vh bf16
  unsigned short* ub = (unsigned short*)(ws + 75497472);   //  8388608 B  U  bf16
  unsigned short* tb = (unsigned short*)(ws + 83886080);   // 16777216 B  t  bf16

  cast_bf16_k<<<(M * DIN / 4 + 255) / 256, 256, 0, stream>>>(x, xb, M * DIN / 4);
  cast_bf16_k<<<(DOUT * R / 4 + 255) / 256, 256, 0, stream>>>(U, ub, DOUT * R / 4);
  scale_cast_k<<<(R * DIN / 4 + 255) / 256, 256, 0, stream>>>(Vh, S, vs,
                                                              R * DIN / 4, DIN / 4);

  // t = x @ (S*Vh)^T : [8192,1024], K=4096, bf16 out (grid 32x4 = 128 blocks)
  gemm256<true><<<dim3(M / 256, R / 256), 512, 0, stream>>>(
      (const __bf16*)xb, (const __bf16*)vs, tb, R, DIN);

  // y = t @ U^T : [8192,4096], K=1024, fp32 out (grid 32x16 = 512 blocks)
  gemm256<false><<<dim3(M / 256, DOUT / 256), 512, 0, stream>>>(
      (const __bf16*)tb, (const __bf16*)ub, y, DOUT, R);
}

// Round 2
// 406.326 us; speedup vs baseline: 1.1054x; 1.1054x over previous
//
#include <hip/hip_runtime.h>
#include <hip/hip_bf16.h>
#include <stdint.h>

// ---------------------------------------------------------------------------
// GSVD layer: y = x @ (U diag(S) Vh)^T, factored as
//   t = x @ (S*Vh)^T   [M=8192, R=1024],  K=4096   (split-K=2 + reduce)
//   y = t @ U^T        [M=8192, O=4096],  K=1024
// bf16 MFMA 16x16x32, fp32 accumulate.
// GEMM: 256x256 tile, BK=64, 8 waves (2Mx4N), 8-phase schedule with counted
// vmcnt (T3+T4), full (row&7)<<4 LDS swizzle (T2/G4), setprio (T5).
// ---------------------------------------------------------------------------

typedef __attribute__((ext_vector_type(8))) __bf16 bf16x8;
typedef __attribute__((ext_vector_type(4))) float f32x4;

#define AS1(p) ((const __attribute__((address_space(1))) void*)(p))
#define AS3(p) ((__attribute__((address_space(3))) void*)(p))

static __device__ __forceinline__ unsigned short f2bf(float f) {
  union { float f; unsigned int u; } c; c.f = f;
  unsigned int u = c.u;
  return (unsigned short)((u + 0x7FFFu + ((u >> 16) & 1u)) >> 16);
}

// fp32 -> bf16 cast, 4 elems/thread
__global__ void cast_bf16_k(const float* __restrict__ in,
                            unsigned short* __restrict__ out, int n4) {
  int gid = blockIdx.x * blockDim.x + threadIdx.x;
  if (gid >= n4) return;
  const float4 v = ((const float4*)in)[gid];
  ushort4 o;
  o.x = f2bf(v.x); o.y = f2bf(v.y); o.z = f2bf(v.z); o.w = f2bf(v.w);
  ((ushort4*)out)[gid] = o;
}

// Vs[r][i] = bf16(S[r] * Vh[r][i])
__global__ void scale_cast_k(const float* __restrict__ Vh,
                             const float* __restrict__ S,
                             unsigned short* __restrict__ out,
                             int n4, int din4) {
  int gid = blockIdx.x * blockDim.x + threadIdx.x;
  if (gid >= n4) return;
  float s = S[gid / din4];
  const float4 v = ((const float4*)Vh)[gid];
  ushort4 o;
  o.x = f2bf(v.x * s); o.y = f2bf(v.y * s);
  o.z = f2bf(v.z * s); o.w = f2bf(v.w * s);
  ((ushort4*)out)[gid] = o;
}

// out[i] = bf16(p[i] + p[i+half]) : split-K reduction, 4 elems/thread
__global__ void reduce2_bf16_k(const float* __restrict__ p,
                               unsigned short* __restrict__ out,
                               int n4, size_t half4) {
  int gid = blockIdx.x * blockDim.x + threadIdx.x;
  if (gid >= n4) return;
  const float4 a = ((const float4*)p)[gid];
  const float4 b = ((const float4*)p)[gid + half4];
  ushort4 o;
  o.x = f2bf(a.x + b.x); o.y = f2bf(a.y + b.y);
  o.z = f2bf(a.z + b.z); o.w = f2bf(a.w + b.w);
  ((ushort4*)out)[gid] = o;
}

// ---------------------------------------------------------------------------
// C[m,n] = sum_{k in z-slice} A[m,k]*B[n,k]  (A:[M,K], B:[N,K] bf16 rm)
// 256x256 tile, BK=64, 512 threads = 8 waves in 2Mx4N, per-wave 128x64 out.
// LDS: 8 regions x 16KB = 128KB: [dbuf(2)][op A/B][half(2)][128 rows x 64 k].
// Swizzle (G4 full): physical byte = logical ^ (((logical>>7)&7)<<4)
//   -> each 8-row stripe spreads its rows across all 8 16B bank-quads.
// Staging: linear global_load_lds dest + inverse-swizzled global source
// (both-sides involution, rule #21); ds_read applies the same XOR.
// 8-phase schedule per 2 K-tiles; vmcnt(4) only at ph3/ph7 (2-deep).
// Split-K: blockIdx.z selects K-slice [z*k_len, (z+1)*k_len); fp32 output
// goes to C + z*zstride. Requires k_len%128==0.
// ---------------------------------------------------------------------------

#define BAR() __builtin_amdgcn_s_barrier()
#define WAITLG0() asm volatile("s_waitcnt lgkmcnt(0)" ::: "memory")
#define WAITLG8() asm volatile("s_waitcnt lgkmcnt(8)" ::: "memory")
#define WAITVM4() asm volatile("s_waitcnt vmcnt(4)" ::: "memory")

template <bool OUT_BF16>
__global__ __launch_bounds__(512)
void gemm256(const __bf16* __restrict__ A, const __bf16* __restrict__ B,
             void* __restrict__ C, int N, int K, int k_len, size_t zstride) {
  __shared__ __bf16 sm[8][8192];  // region = dbuf*4 + op*2 + half, 16KB each

  const int t    = threadIdx.x;
  const int lane = t & 63;
  const int wid  = __builtin_amdgcn_readfirstlane(t >> 6);
  const int q    = lane >> 4;   // k-group within MFMA fragment
  const int lr   = lane & 15;   // row/col within 16x16 fragment

  const int bm = blockIdx.x, bn = blockIdx.y;
  const int kz = blockIdx.z * k_len;
  const int wmh = wid >> 2;          // which A half this wave consumes
  const int wn4 = wid & 3;
  const int bh  = wn4 >> 1;          // which B half this wave consumes
  const int wnr = (wn4 & 1) * 64;    // row base inside B half

  // swizzled k-byte offsets for ds_read: XOR row bits [2:0] into byte [6:4]
  const int kx  = (lr & 7) << 4;        // row&7 == lr&7 (16 | 8)
  const int ko0 = (q * 16) ^ kx;        // k-half 0
  const int ko1 = (64 + q * 16) ^ kx;   // k-half 1

  const size_t halfK = (size_t)128 * K;

  // staging source pointers: lane's 16B chunk, inverse-swizzled
  const __bf16* pA[2]; const __bf16* pB[2];
#pragma unroll
  for (int li = 0; li < 2; ++li) {
    const int phys = li * 8192 + wid * 1024 + lane * 16;  // linear LDS byte
    const int lg   = phys ^ (((phys >> 7) & 7) << 4);     // logical byte
    const int grow = lg >> 7, gkb = lg & 127;
    pA[li] = A + (size_t)(bm * 256 + grow) * K + (gkb >> 1) + kz;
    pB[li] = B + (size_t)(bn * 256 + grow) * K + (gkb >> 1) + kz;
  }

#define STAGE(P, reg, h, tt)                                                   \
  {                                                                            \
    __bf16* l_ = &sm[(reg)][0] + wid * 512;                                    \
    __builtin_amdgcn_global_load_lds(AS1(P[0] + (h) * halfK + (size_t)(tt) * 64), \
                                     AS3(l_), 16, 0, 0);                       \
    __builtin_amdgcn_global_load_lds(AS1(P[1] + (h) * halfK + (size_t)(tt) * 64), \
                                     AS3(l_ + 4096), 16, 0, 0);                \
  }

#define LDA(d, mf, kh) \
  (*(const bf16x8*)((const char*)&sm[(d) * 4 + wmh][0] + ((mf) * 16 + lr) * 128 + ko##kh))
#define LDB(d, nf, kh) \
  (*(const bf16x8*)((const char*)&sm[(d) * 4 + 2 + bh][0] + (wnr + (nf) * 16 + lr) * 128 + ko##kh))

#define READ_A(d, mh, dst)                                                    \
  dst[0][0] = LDA(d, (mh) * 4 + 0, 0); dst[0][1] = LDA(d, (mh) * 4 + 0, 1);   \
  dst[1][0] = LDA(d, (mh) * 4 + 1, 0); dst[1][1] = LDA(d, (mh) * 4 + 1, 1);   \
  dst[2][0] = LDA(d, (mh) * 4 + 2, 0); dst[2][1] = LDA(d, (mh) * 4 + 2, 1);   \
  dst[3][0] = LDA(d, (mh) * 4 + 3, 0); dst[3][1] = LDA(d, (mh) * 4 + 3, 1);

#define READ_B(d, nh, dst)                                                    \
  dst[0][0] = LDB(d, (nh) * 2 + 0, 0); dst[0][1] = LDB(d, (nh) * 2 + 0, 1);   \
  dst[1][0] = LDB(d, (nh) * 2 + 1, 0); dst[1][1] = LDB(d, (nh) * 2 + 1, 1);

#define MFMA_Q(mh, nh, ar, br)                                                \
  __builtin_amdgcn_s_setprio(1);                                              \
  _Pragma("unroll") for (int mi = 0; mi < 4; ++mi) {                          \
    _Pragma("unroll") for (int ni = 0; ni < 2; ++ni) {                        \
      acc[(mh) * 4 + mi][(nh) * 2 + ni] =                                     \
          __builtin_amdgcn_mfma_f32_16x16x32_bf16(                            \
              ar[mi][0], br[ni][0], acc[(mh) * 4 + mi][(nh) * 2 + ni], 0, 0, 0); \
      acc[(mh) * 4 + mi][(nh) * 2 + ni] =                                     \
          __builtin_amdgcn_mfma_f32_16x16x32_bf16(                            \
              ar[mi][1], br[ni][1], acc[(mh) * 4 + mi][(nh) * 2 + ni], 0, 0, 0); \
    }                                                                         \
  }                                                                           \
  __builtin_amdgcn_s_setprio(0);

  f32x4 acc[8][4] = {};
  bf16x8 aA[4][2], aB[4][2], bA[2][2], bB[2][2];

  const int NT = k_len >> 6;  // K-tiles of 64 within this z-slice

  // prologue: tile0 -> dbuf0 {A0,A1,B0,B1}; tile1 -> dbuf1 {A0,A1}
  STAGE(pA, 0, 0, 0); STAGE(pA, 1, 1, 0);
  STAGE(pB, 2, 0, 0); STAGE(pB, 3, 1, 0);
  STAGE(pA, 4, 0, 1); STAGE(pA, 5, 1, 1);
  WAITVM4();  // tile0 fully landed; tile1 A-halves still in flight
  BAR();

  for (int i = 0; i < NT / 2; ++i) {
    const int t1 = 2 * i + 1;
    const int t2 = (2 * i + 2 < NT) ? 2 * i + 2 : NT - 1;  // clamped: tail
    const int t3 = (2 * i + 3 < NT) ? 2 * i + 3 : NT - 1;  // stages unread

    // ---- K-tile 2i from dbuf0 ----
    // ph0: read A-mh0 + B-nh0 (12 ds_reads); stage dbuf1.B0 <- t1
    READ_A(0, 0, aA);
    READ_B(0, 0, bA);
    STAGE(pB, 6, 0, t1);
    WAITLG8();
    BAR(); WAITLG0();
    MFMA_Q(0, 0, aA, bA);
    BAR();
    // ph1: read A-mh1; stage dbuf1.B1 <- t1
    READ_A(0, 1, aB);
    STAGE(pB, 7, 1, t1);
    BAR(); WAITLG0();
    MFMA_Q(1, 0, aB, bA);
    BAR();
    // ph2: read B-nh1; stage dbuf0.A0 <- t2 (dbuf0.A reads done at ph1)
    READ_B(0, 1, bB);
    STAGE(pA, 0, 0, t2);
    BAR(); WAITLG0();
    MFMA_Q(0, 1, aA, bB);
    BAR();
    // ph3: stage dbuf0.A1 <- t2; vmcnt(4) => t1 + prev A fully landed
    STAGE(pA, 1, 1, t2);
    WAITVM4();
    BAR();
    MFMA_Q(1, 1, aB, bB);
    BAR();

    // ---- K-tile 2i+1 from dbuf1 ----
    // ph4: stage dbuf0.B0 <- t2 (dbuf0.B reads done at ph2)
    READ_A(1, 0, aA);
    READ_B(1, 0, bA);
    STAGE(pB, 2, 0, t2);
    WAITLG8();
    BAR(); WAITLG0();
    MFMA_Q(0, 0, aA, bA);
    BAR();
    // ph5: stage dbuf0.B1 <- t2
    READ_A(1, 1, aB);
    STAGE(pB, 3, 1, t2);
    BAR(); WAITLG0();
    MFMA_Q(1, 0, aB, bA);
    BAR();
    // ph6: stage dbuf1.A0 <- t3 (dbuf1.A reads done at ph5)
    READ_B(1, 1, bB);
    STAGE(pA, 4, 0, t3);
    BAR(); WAITLG0();
    MFMA_Q(0, 1, aA, bB);
    BAR();
    // ph7: stage dbuf1.A1 <- t3; vmcnt(4) => t2 fully landed for next ph0..3
    STAGE(pA, 5, 1, t3);
    WAITVM4();
    BAR();
    MFMA_Q(1, 1, aB, bB);
    BAR();
  }

  // epilogue: C/D layout col=lane&15, row=(lane>>4)*4+reg  [m89/m91 verified]
  const int wm = wmh * 128;
  const int wn = wn4 * 64;
  const int r0 = q * 4;
  float* Cf = (float*)C + blockIdx.z * zstride;
#pragma unroll
  for (int mf = 0; mf < 8; ++mf) {
#pragma unroll
    for (int nf = 0; nf < 4; ++nf) {
      const int col = bn * 256 + wn + nf * 16 + lr;
      const size_t rb = (size_t)(bm * 256 + wm + mf * 16 + r0);
#pragma unroll
      for (int r = 0; r < 4; ++r) {
        const float v = acc[mf][nf][r];
        if (OUT_BF16) ((unsigned short*)C)[(rb + r) * N + col] = f2bf(v);
        else          Cf[(rb + r) * N + col] = v;
      }
    }
  }
}

extern "C" void kernel_launch(void* const* d_in, const int* in_sizes, int n_in,
                              void* d_out, int out_size, void* d_ws, size_t ws_size,
                              hipStream_t stream) {
  const float* x  = (const float*)d_in[0];  // [4,2048,4096] = [8192,4096]
  const float* U  = (const float*)d_in[1];  // [4096,1024]
  const float* S  = (const float*)d_in[2];  // [1024]
  const float* Vh = (const float*)d_in[3];  // [1024,4096]
  float* y = (float*)d_out;                 // [8192,4096] fp32

  const int M = 8192, DIN = 4096, DOUT = 4096, R = 1024;

  char* ws = (char*)d_ws;
  unsigned short* xb = (unsigned short*)(ws);              // 67108864 B  x  bf16
  unsigned short* vs = (unsigned short*)(ws + 67108864);   //  8388608 B  S*Vh bf16
  unsigned short* ub = (unsigned short*)(ws + 75497472);   //  8388608 B  U  bf16
  unsigned short* tb = (unsigned short*)(ws + 83886080);   // 16777216 B  t  bf16
  float*          tp = (float*)(ws + 100663296);           // 67108864 B  split-K partials

  cast_bf16_k<<<(M * DIN / 4 + 255) / 256, 256, 0, stream>>>(x, xb, M * DIN / 4);
  cast_bf16_k<<<(DOUT * R / 4 + 255) / 256, 256, 0, stream>>>(U, ub, DOUT * R / 4);
  scale_cast_k<<<(R * DIN / 4 + 255) / 256, 256, 0, stream>>>(Vh, S, vs,
                                                              R * DIN / 4, DIN / 4);

  if (ws_size >= 167772160) {
    // t = x @ (S*Vh)^T split-K=2: 32x4x2 = 256 blocks (full chip), fp32 partials
    gemm256<false><<<dim3(M / 256, R / 256, 2), 512, 0, stream>>>(
        (const __bf16*)xb, (const __bf16*)vs, tp, R, DIN, DIN / 2,
        (size_t)M * R);
    reduce2_bf16_k<<<(M * R / 4 + 255) / 256, 256, 0, stream>>>(
        tp, tb, M * R / 4, (size_t)M * R / 4);
  } else {
    // fallback: no split (128 blocks, half chip)
    gemm256<true><<<dim3(M / 256, R / 256, 1), 512, 0, stream>>>(
        (const __bf16*)xb, (const __bf16*)vs, tb, R, DIN, DIN, 0);
  }

  // y = t @ U^T : [8192,4096], K=1024, fp32 out (grid 32x16 = 512 blocks)
  gemm256<false><<<dim3(M / 256, DOUT / 256, 1), 512, 0, stream>>>(
      (const __bf16*)tb, (const __bf16*)ub, y, DOUT, R, R, 0);
}

// Round 3
// 404.635 us; speedup vs baseline: 1.1100x; 1.0042x over previous
//
#include <hip/hip_runtime.h>
#include <hip/hip_bf16.h>
#include <stdint.h>

// ---------------------------------------------------------------------------
// GSVD layer: y = x @ (U diag(S) Vh)^T, factored as
//   t = x @ (S*Vh)^T   [M=8192, R=1024],  K=4096   (split-K=2 + reduce)
//   y = t @ U^T        [M=8192, O=4096],  K=1024
// bf16 MFMA 16x16x32, fp32 accumulate.
// GEMM: 256x256 tile, BK=64, 8 waves (2Mx4N), 8-phase schedule with counted
// vmcnt (T3+T4), full (row&7)<<4 LDS swizzle (T2/G4), setprio (T5),
// XCD-chunked block swizzle (T1) for L2 panel reuse.
// ---------------------------------------------------------------------------

typedef __attribute__((ext_vector_type(8))) __bf16 bf16x8;
typedef __attribute__((ext_vector_type(4))) float f32x4;

#define AS1(p) ((const __attribute__((address_space(1))) void*)(p))
#define AS3(p) ((__attribute__((address_space(3))) void*)(p))

static __device__ __forceinline__ unsigned short f2bf(float f) {
  union { float f; unsigned int u; } c; c.f = f;
  unsigned int u = c.u;
  return (unsigned short)((u + 0x7FFFu + ((u >> 16) & 1u)) >> 16);
}

// fp32 -> bf16 cast, 4 elems/thread
__global__ void cast_bf16_k(const float* __restrict__ in,
                            unsigned short* __restrict__ out, int n4) {
  int gid = blockIdx.x * blockDim.x + threadIdx.x;
  if (gid >= n4) return;
  const float4 v = ((const float4*)in)[gid];
  ushort4 o;
  o.x = f2bf(v.x); o.y = f2bf(v.y); o.z = f2bf(v.z); o.w = f2bf(v.w);
  ((ushort4*)out)[gid] = o;
}

// Vs[r][i] = bf16(S[r] * Vh[r][i])
__global__ void scale_cast_k(const float* __restrict__ Vh,
                             const float* __restrict__ S,
                             unsigned short* __restrict__ out,
                             int n4, int din4) {
  int gid = blockIdx.x * blockDim.x + threadIdx.x;
  if (gid >= n4) return;
  float s = S[gid / din4];
  const float4 v = ((const float4*)Vh)[gid];
  ushort4 o;
  o.x = f2bf(v.x * s); o.y = f2bf(v.y * s);
  o.z = f2bf(v.z * s); o.w = f2bf(v.w * s);
  ((ushort4*)out)[gid] = o;
}

// out[i] = bf16(p[i] + p[i+half]) : split-K reduction, 4 elems/thread
__global__ void reduce2_bf16_k(const float* __restrict__ p,
                               unsigned short* __restrict__ out,
                               int n4, size_t half4) {
  int gid = blockIdx.x * blockDim.x + threadIdx.x;
  if (gid >= n4) return;
  const float4 a = ((const float4*)p)[gid];
  const float4 b = ((const float4*)p)[gid + half4];
  ushort4 o;
  o.x = f2bf(a.x + b.x); o.y = f2bf(a.y + b.y);
  o.z = f2bf(a.z + b.z); o.w = f2bf(a.w + b.w);
  ((ushort4*)out)[gid] = o;
}

// ---------------------------------------------------------------------------
// C[m,n] = sum_{k in z-slice} A[m,k]*B[n,k]  (A:[M,K], B:[N,K] bf16 rm)
// 256x256 tile, BK=64, 512 threads = 8 waves in 2Mx4N, per-wave 128x64 out.
// LDS: 8 regions x 16KB = 128KB: [dbuf(2)][op A/B][half(2)][128 rows x 64 k].
// Swizzle (G4 full): physical byte = logical ^ (((logical>>7)&7)<<4).
// Staging: linear global_load_lds dest + inverse-swizzled global source.
// 8-phase schedule per 2 K-tiles; vmcnt(4) only at ph3/ph7 (2-deep).
//
// XCD-chunked block swizzle (T1): HW round-robins consecutive wgid across
// the 8 XCDs, so chunk id c = wgid&7 stays on ONE XCD. Each chunk covers a
// contiguous CBM x CBN rectangle of output tiles (and one z slice), so the
// chunk's A/B panels are fetched into that XCD's private L2 once and shared.
// Requires gridDim product == 8*CBM*CBN*(z chunks); mapping is bijective.
// ---------------------------------------------------------------------------

#define BAR() __builtin_amdgcn_s_barrier()
#define WAITLG0() asm volatile("s_waitcnt lgkmcnt(0)" ::: "memory")
#define WAITLG8() asm volatile("s_waitcnt lgkmcnt(8)" ::: "memory")
#define WAITVM4() asm volatile("s_waitcnt vmcnt(4)" ::: "memory")

template <bool OUT_BF16>
__global__ __launch_bounds__(512)
void gemm256(const __bf16* __restrict__ A, const __bf16* __restrict__ B,
             void* __restrict__ C, int N, int K, int k_len, size_t zstride,
             int CBM, int CBN, int CHN, int nchunks_mn) {
  __shared__ __bf16 sm[8][8192];  // region = dbuf*4 + op*2 + half, 16KB each

  const int t    = threadIdx.x;
  const int lane = t & 63;
  const int wid  = __builtin_amdgcn_readfirstlane(t >> 6);
  const int q    = lane >> 4;   // k-group within MFMA fragment
  const int lr   = lane & 15;   // row/col within 16x16 fragment

  // ---- T1: XCD-chunked bijective remap of (bm, bn, z) ----
  const unsigned wgid =
      (blockIdx.z * gridDim.y + blockIdx.y) * gridDim.x + blockIdx.x;
  const unsigned c = wgid & 7u;          // XCD id (HW round-robin)
  const unsigned j = wgid >> 3;          // index within chunk
  const unsigned zc  = c / (unsigned)nchunks_mn;
  const unsigned rem = c - zc * (unsigned)nchunks_mn;
  const unsigned cm  = rem / (unsigned)CHN;
  const unsigned cn  = rem - cm * (unsigned)CHN;
  const int bm = (int)(cm * (unsigned)CBM + j / (unsigned)CBN);
  const int bn = (int)(cn * (unsigned)CBN + j % (unsigned)CBN);
  const int kz = (int)zc * k_len;

  const int wmh = wid >> 2;          // which A half this wave consumes
  const int wn4 = wid & 3;
  const int bh  = wn4 >> 1;          // which B half this wave consumes
  const int wnr = (wn4 & 1) * 64;    // row base inside B half

  // swizzled k-byte offsets for ds_read: XOR row bits [2:0] into byte [6:4]
  const int kx  = (lr & 7) << 4;
  const int ko0 = (q * 16) ^ kx;        // k-half 0
  const int ko1 = (64 + q * 16) ^ kx;   // k-half 1

  const size_t halfK = (size_t)128 * K;

  // staging source pointers: lane's 16B chunk, inverse-swizzled
  const __bf16* pA[2]; const __bf16* pB[2];
#pragma unroll
  for (int li = 0; li < 2; ++li) {
    const int phys = li * 8192 + wid * 1024 + lane * 16;  // linear LDS byte
    const int lg   = phys ^ (((phys >> 7) & 7) << 4);     // logical byte
    const int grow = lg >> 7, gkb = lg & 127;
    pA[li] = A + (size_t)(bm * 256 + grow) * K + (gkb >> 1) + kz;
    pB[li] = B + (size_t)(bn * 256 + grow) * K + (gkb >> 1) + kz;
  }

#define STAGE(P, reg, h, tt)                                                   \
  {                                                                            \
    __bf16* l_ = &sm[(reg)][0] + wid * 512;                                    \
    __builtin_amdgcn_global_load_lds(AS1(P[0] + (h) * halfK + (size_t)(tt) * 64), \
                                     AS3(l_), 16, 0, 0);                       \
    __builtin_amdgcn_global_load_lds(AS1(P[1] + (h) * halfK + (size_t)(tt) * 64), \
                                     AS3(l_ + 4096), 16, 0, 0);                \
  }

#define LDA(d, mf, kh) \
  (*(const bf16x8*)((const char*)&sm[(d) * 4 + wmh][0] + ((mf) * 16 + lr) * 128 + ko##kh))
#define LDB(d, nf, kh) \
  (*(const bf16x8*)((const char*)&sm[(d) * 4 + 2 + bh][0] + (wnr + (nf) * 16 + lr) * 128 + ko##kh))

#define READ_A(d, mh, dst)                                                    \
  dst[0][0] = LDA(d, (mh) * 4 + 0, 0); dst[0][1] = LDA(d, (mh) * 4 + 0, 1);   \
  dst[1][0] = LDA(d, (mh) * 4 + 1, 0); dst[1][1] = LDA(d, (mh) * 4 + 1, 1);   \
  dst[2][0] = LDA(d, (mh) * 4 + 2, 0); dst[2][1] = LDA(d, (mh) * 4 + 2, 1);   \
  dst[3][0] = LDA(d, (mh) * 4 + 3, 0); dst[3][1] = LDA(d, (mh) * 4 + 3, 1);

#define READ_B(d, nh, dst)                                                    \
  dst[0][0] = LDB(d, (nh) * 2 + 0, 0); dst[0][1] = LDB(d, (nh) * 2 + 0, 1);   \
  dst[1][0] = LDB(d, (nh) * 2 + 1, 0); dst[1][1] = LDB(d, (nh) * 2 + 1, 1);

#define MFMA_Q(mh, nh, ar, br)                                                \
  __builtin_amdgcn_s_setprio(1);                                              \
  _Pragma("unroll") for (int mi = 0; mi < 4; ++mi) {                          \
    _Pragma("unroll") for (int ni = 0; ni < 2; ++ni) {                        \
      acc[(mh) * 4 + mi][(nh) * 2 + ni] =                                     \
          __builtin_amdgcn_mfma_f32_16x16x32_bf16(                            \
              ar[mi][0], br[ni][0], acc[(mh) * 4 + mi][(nh) * 2 + ni], 0, 0, 0); \
      acc[(mh) * 4 + mi][(nh) * 2 + ni] =                                     \
          __builtin_amdgcn_mfma_f32_16x16x32_bf16(                            \
              ar[mi][1], br[ni][1], acc[(mh) * 4 + mi][(nh) * 2 + ni], 0, 0, 0); \
    }                                                                         \
  }                                                                           \
  __builtin_amdgcn_s_setprio(0);

  f32x4 acc[8][4] = {};
  bf16x8 aA[4][2], aB[4][2], bA[2][2], bB[2][2];

  const int NT = k_len >> 6;  // K-tiles of 64 within this z-slice

  // prologue: tile0 -> dbuf0 {A0,A1,B0,B1}; tile1 -> dbuf1 {A0,A1}
  STAGE(pA, 0, 0, 0); STAGE(pA, 1, 1, 0);
  STAGE(pB, 2, 0, 0); STAGE(pB, 3, 1, 0);
  STAGE(pA, 4, 0, 1); STAGE(pA, 5, 1, 1);
  WAITVM4();  // tile0 fully landed; tile1 A-halves still in flight
  BAR();

  for (int i = 0; i < NT / 2; ++i) {
    const int t1 = 2 * i + 1;
    const int t2 = (2 * i + 2 < NT) ? 2 * i + 2 : NT - 1;  // clamped: tail
    const int t3 = (2 * i + 3 < NT) ? 2 * i + 3 : NT - 1;  // stages unread

    // ---- K-tile 2i from dbuf0 ----
    // ph0: read A-mh0 + B-nh0 (12 ds_reads); stage dbuf1.B0 <- t1
    READ_A(0, 0, aA);
    READ_B(0, 0, bA);
    STAGE(pB, 6, 0, t1);
    WAITLG8();
    BAR(); WAITLG0();
    MFMA_Q(0, 0, aA, bA);
    BAR();
    // ph1: read A-mh1; stage dbuf1.B1 <- t1
    READ_A(0, 1, aB);
    STAGE(pB, 7, 1, t1);
    BAR(); WAITLG0();
    MFMA_Q(1, 0, aB, bA);
    BAR();
    // ph2: read B-nh1; stage dbuf0.A0 <- t2 (dbuf0.A reads done at ph1)
    READ_B(0, 1, bB);
    STAGE(pA, 0, 0, t2);
    BAR(); WAITLG0();
    MFMA_Q(0, 1, aA, bB);
    BAR();
    // ph3: stage dbuf0.A1 <- t2; vmcnt(4) => t1 + prev A fully landed
    STAGE(pA, 1, 1, t2);
    WAITVM4();
    BAR();
    MFMA_Q(1, 1, aB, bB);
    BAR();

    // ---- K-tile 2i+1 from dbuf1 ----
    // ph4: stage dbuf0.B0 <- t2 (dbuf0.B reads done at ph2)
    READ_A(1, 0, aA);
    READ_B(1, 0, bA);
    STAGE(pB, 2, 0, t2);
    WAITLG8();
    BAR(); WAITLG0();
    MFMA_Q(0, 0, aA, bA);
    BAR();
    // ph5: stage dbuf0.B1 <- t2
    READ_A(1, 1, aB);
    STAGE(pB, 3, 1, t2);
    BAR(); WAITLG0();
    MFMA_Q(1, 0, aB, bA);
    BAR();
    // ph6: stage dbuf1.A0 <- t3 (dbuf1.A reads done at ph5)
    READ_B(1, 1, bB);
    STAGE(pA, 4, 0, t3);
    BAR(); WAITLG0();
    MFMA_Q(0, 1, aA, bB);
    BAR();
    // ph7: stage dbuf1.A1 <- t3; vmcnt(4) => t2 fully landed for next ph0..3
    STAGE(pA, 5, 1, t3);
    WAITVM4();
    BAR();
    MFMA_Q(1, 1, aB, bB);
    BAR();
  }

  // epilogue: C/D layout col=lane&15, row=(lane>>4)*4+reg  [m89/m91 verified]
  const int wm = wmh * 128;
  const int wn = wn4 * 64;
  const int r0 = q * 4;
  float* Cf = (float*)C + zc * zstride;
#pragma unroll
  for (int mf = 0; mf < 8; ++mf) {
#pragma unroll
    for (int nf = 0; nf < 4; ++nf) {
      const int col = bn * 256 + wn + nf * 16 + lr;
      const size_t rb = (size_t)(bm * 256 + wm + mf * 16 + r0);
#pragma unroll
      for (int r = 0; r < 4; ++r) {
        const float v = acc[mf][nf][r];
        if (OUT_BF16) ((unsigned short*)C)[(rb + r) * N + col] = f2bf(v);
        else          Cf[(rb + r) * N + col] = v;
      }
    }
  }
}

extern "C" void kernel_launch(void* const* d_in, const int* in_sizes, int n_in,
                              void* d_out, int out_size, void* d_ws, size_t ws_size,
                              hipStream_t stream) {
  const float* x  = (const float*)d_in[0];  // [4,2048,4096] = [8192,4096]
  const float* U  = (const float*)d_in[1];  // [4096,1024]
  const float* S  = (const float*)d_in[2];  // [1024]
  const float* Vh = (const float*)d_in[3];  // [1024,4096]
  float* y = (float*)d_out;                 // [8192,4096] fp32

  const int M = 8192, DIN = 4096, DOUT = 4096, R = 1024;

  char* ws = (char*)d_ws;
  unsigned short* xb = (unsigned short*)(ws);              // 67108864 B  x  bf16
  unsigned short* vs = (unsigned short*)(ws + 67108864);   //  8388608 B  S*Vh bf16
  unsigned short* ub = (unsigned short*)(ws + 75497472);   //  8388608 B  U  bf16
  unsigned short* tb = (unsigned short*)(ws + 83886080);   // 16777216 B  t  bf16
  float*          tp = (float*)(ws + 100663296);           // 67108864 B  split-K partials

  cast_bf16_k<<<(M * DIN / 4 + 255) / 256, 256, 0, stream>>>(x, xb, M * DIN / 4);
  cast_bf16_k<<<(DOUT * R / 4 + 255) / 256, 256, 0, stream>>>(U, ub, DOUT * R / 4);
  scale_cast_k<<<(R * DIN / 4 + 255) / 256, 256, 0, stream>>>(Vh, S, vs,
                                                              R * DIN / 4, DIN / 4);

  if (ws_size >= 167772160) {
    // t = x @ (S*Vh)^T split-K=2: 32x4x2 = 256 blocks (full chip), fp32 partials.
    // Chunks: 8 XCDs = 4 (bm) x 1 (bn) x 2 (z); each chunk 8bm x 4bn = 32 blocks.
    gemm256<false><<<dim3(M / 256, R / 256, 2), 512, 0, stream>>>(
        (const __bf16*)xb, (const __bf16*)vs, tp, R, DIN, DIN / 2,
        (size_t)M * R, /*CBM=*/8, /*CBN=*/4, /*CHN=*/1, /*nchunks_mn=*/4);
    reduce2_bf16_k<<<(M * R / 4 + 255) / 256, 256, 0, stream>>>(
        tp, tb, M * R / 4, (size_t)M * R / 4);
  } else {
    // fallback: no split (128 blocks, half chip). Chunks: 8 = 8(bm) x 1(bn),
    // each chunk 4bm x 4bn = 16 blocks.
    gemm256<true><<<dim3(M / 256, R / 256, 1), 512, 0, stream>>>(
        (const __bf16*)xb, (const __bf16*)vs, tb, R, DIN, DIN, 0,
        /*CBM=*/4, /*CBN=*/4, /*CHN=*/1, /*nchunks_mn=*/8);
  }

  // y = t @ U^T : [8192,4096], K=1024, fp32 out, 32x16 = 512 blocks.
  // Chunks: 8 XCDs = 4 (bm) x 2 (bn); each chunk 8bm x 8bn = 64 blocks.
  gemm256<false><<<dim3(M / 256, DOUT / 256, 1), 512, 0, stream>>>(
      (const __bf16*)tb, (const __bf16*)ub, y, DOUT, R, R, 0,
      /*CBM=*/8, /*CBN=*/8, /*CHN=*/2, /*nchunks_mn=*/8);
}

// Round 4
// 394.470 us; speedup vs baseline: 1.1386x; 1.0258x over previous
//
#include <hip/hip_runtime.h>
#include <hip/hip_bf16.h>
#include <stdint.h>

// ---------------------------------------------------------------------------
// GSVD layer: y = x @ (U diag(S) Vh)^T, factored as
//   t = x @ (S*Vh)^T   [M=8192, R=1024],  K=4096   (split-K=2 + reduce)
//   y = t @ U^T        [M=8192, O=4096],  K=1024   (persistent 2-tile stream)
// bf16 MFMA 16x16x32, fp32 accumulate.
// GEMM: 256x256 tile, BK=64, 8 waves (2Mx4N), 8-phase schedule with counted
// vmcnt (T3+T4), (row&7)<<4 LDS swizzle (T2/G4), setprio (T5), XCD chunking.
// NEW: multi-tile K-stream per block — the stage pipeline stays hot across
// output tiles (tail dummy stages become next tile's prologue; A-panel
// shared between the paired tiles -> L2-hot restage).
// ---------------------------------------------------------------------------

typedef __attribute__((ext_vector_type(8))) __bf16 bf16x8;
typedef __attribute__((ext_vector_type(4))) float f32x4;

#define AS1(p) ((const __attribute__((address_space(1))) void*)(p))
#define AS3(p) ((__attribute__((address_space(3))) void*)(p))

static __device__ __forceinline__ unsigned short f2bf(float f) {
  union { float f; unsigned int u; } c; c.f = f;
  unsigned int u = c.u;
  return (unsigned short)((u + 0x7FFFu + ((u >> 16) & 1u)) >> 16);
}

// Fused prep: cast x, cast U, scale+cast Vh — one dispatch, segments are
// block-aligned (all n4 multiples of 256) so branches are block-uniform.
__global__ void prep_k(const float* __restrict__ x, const float* __restrict__ U,
                       const float* __restrict__ Vh, const float* __restrict__ S,
                       unsigned short* __restrict__ xb,
                       unsigned short* __restrict__ ub,
                       unsigned short* __restrict__ vs,
                       int xN4, int uN4, int vN4, int din4) {
  int gid = blockIdx.x * blockDim.x + threadIdx.x;
  if (gid < xN4) {
    const float4 v = ((const float4*)x)[gid];
    ushort4 o;
    o.x = f2bf(v.x); o.y = f2bf(v.y); o.z = f2bf(v.z); o.w = f2bf(v.w);
    ((ushort4*)xb)[gid] = o;
  } else if (gid < xN4 + uN4) {
    const int g = gid - xN4;
    const float4 v = ((const float4*)U)[g];
    ushort4 o;
    o.x = f2bf(v.x); o.y = f2bf(v.y); o.z = f2bf(v.z); o.w = f2bf(v.w);
    ((ushort4*)ub)[g] = o;
  } else {
    const int g = gid - xN4 - uN4;
    if (g >= vN4) return;
    const float s = S[g / din4];
    const float4 v = ((const float4*)Vh)[g];
    ushort4 o;
    o.x = f2bf(v.x * s); o.y = f2bf(v.y * s);
    o.z = f2bf(v.z * s); o.w = f2bf(v.w * s);
    ((ushort4*)vs)[g] = o;
  }
}

// out[i] = bf16(p[i] + p[i+half]) : split-K reduction
__global__ void reduce2_bf16_k(const float* __restrict__ p,
                               unsigned short* __restrict__ out,
                               int n4, size_t half4) {
  int gid = blockIdx.x * blockDim.x + threadIdx.x;
  if (gid >= n4) return;
  const float4 a = ((const float4*)p)[gid];
  const float4 b = ((const float4*)p)[gid + half4];
  ushort4 o;
  o.x = f2bf(a.x + b.x); o.y = f2bf(a.y + b.y);
  o.z = f2bf(a.z + b.z); o.w = f2bf(a.w + b.w);
  ((ushort4*)out)[gid] = o;
}

// ---------------------------------------------------------------------------
// C[m,n] = sum_{k slice} A[m,k]*B[n,k]  (A:[M,K], B:[N,K] bf16 rm)
// Persistent stream: block computes `tiles` output tiles (bm fixed, bn
// advancing by bn_step) over a K-tile stream of length tiles*NT. Stage
// indices run ahead in stream space; source mapping: ktile = s & (NT-1),
// +badv element offset when s >= NT (second tile's B panel; A shared).
// Requires k_len/64 = NT a power of two (shapes: 16 and 32).
// ---------------------------------------------------------------------------

#define BAR() __builtin_amdgcn_s_barrier()
#define WAITLG0() asm volatile("s_waitcnt lgkmcnt(0)" ::: "memory")
#define WAITLG8() asm volatile("s_waitcnt lgkmcnt(8)" ::: "memory")
#define WAITVM4() asm volatile("s_waitcnt vmcnt(4)" ::: "memory")

template <bool OUT_BF16>
__global__ __launch_bounds__(512)
void gemm256(const __bf16* __restrict__ A, const __bf16* __restrict__ B,
             void* __restrict__ C, int N, int K, int k_len, size_t zstride,
             int CBM, int CBN, int CHN, int nchunks_mn, int tiles, int bn_step) {
  __shared__ __bf16 sm[8][8192];  // region = dbuf*4 + op*2 + half, 16KB each

  const int t    = threadIdx.x;
  const int lane = t & 63;
  const int wid  = __builtin_amdgcn_readfirstlane(t >> 6);
  const int q    = lane >> 4;
  const int lr   = lane & 15;

  // ---- XCD-chunked bijective remap of (bm, bn0, z) ----
  const unsigned wgid =
      (blockIdx.z * gridDim.y + blockIdx.y) * gridDim.x + blockIdx.x;
  const unsigned c = wgid & 7u;
  const unsigned j = wgid >> 3;
  const unsigned zc  = c / (unsigned)nchunks_mn;
  const unsigned rem = c - zc * (unsigned)nchunks_mn;
  const unsigned cm  = rem / (unsigned)CHN;
  const unsigned cn  = rem - cm * (unsigned)CHN;
  const int bm  = (int)(cm * (unsigned)CBM + j / (unsigned)CBN);
  const int bn0 = (int)(cn * (unsigned)CBN + j % (unsigned)CBN);
  const int kz  = (int)zc * k_len;

  const int wmh = wid >> 2;
  const int wn4 = wid & 3;
  const int bh  = wn4 >> 1;
  const int wnr = (wn4 & 1) * 64;

  // swizzled k-byte offsets for ds_read: XOR row bits [2:0] into byte [6:4]
  const int kx  = (lr & 7) << 4;
  const int ko0 = (q * 16) ^ kx;
  const int ko1 = (64 + q * 16) ^ kx;

  const size_t halfK = (size_t)128 * K;
  const int    NT    = k_len >> 6;          // K-tiles per output tile (pow2)
  const int    NTm1  = NT - 1;
  const int    TOT   = NT * tiles;          // stream length
  const size_t badv  = (size_t)bn_step * 256 * K;  // B advance for tile 2

  // staging source pointers: lane's 16B chunk, inverse-swizzled
  const __bf16* pA[2]; const __bf16* pB[2];
#pragma unroll
  for (int li = 0; li < 2; ++li) {
    const int phys = li * 8192 + wid * 1024 + lane * 16;  // linear LDS byte
    const int lg   = phys ^ (((phys >> 7) & 7) << 4);     // logical byte
    const int grow = lg >> 7, gkb = lg & 127;
    pA[li] = A + (size_t)(bm * 256 + grow) * K + (gkb >> 1) + kz;
    pB[li] = B + (size_t)(bn0 * 256 + grow) * K + (gkb >> 1) + kz;
  }

#define GLL(p, l) __builtin_amdgcn_global_load_lds(AS1(p), AS3(l), 16, 0, 0)

#define STAGE_A(reg, h, s)                                                     \
  {                                                                            \
    const int s_ = (s) < TOT ? (s) : TOT - 1;                                  \
    const size_t off = (size_t)(s_ & NTm1) * 64;                               \
    __bf16* l_ = &sm[(reg)][0] + wid * 512;                                    \
    GLL(pA[0] + (h) * halfK + off, l_);                                        \
    GLL(pA[1] + (h) * halfK + off, l_ + 4096);                                 \
  }

#define STAGE_B(reg, h, s)                                                     \
  {                                                                            \
    const int s_ = (s) < TOT ? (s) : TOT - 1;                                  \
    const size_t off = (size_t)(s_ & NTm1) * 64 + (s_ >= NT ? badv : 0);       \
    __bf16* l_ = &sm[(reg)][0] + wid * 512;                                    \
    GLL(pB[0] + (h) * halfK + off, l_);                                        \
    GLL(pB[1] + (h) * halfK + off, l_ + 4096);                                 \
  }

#define LDA(d, mf, kh) \
  (*(const bf16x8*)((const char*)&sm[(d) * 4 + wmh][0] + ((mf) * 16 + lr) * 128 + ko##kh))
#define LDB(d, nf, kh) \
  (*(const bf16x8*)((const char*)&sm[(d) * 4 + 2 + bh][0] + (wnr + (nf) * 16 + lr) * 128 + ko##kh))

#define READ_A(d, mh, dst)                                                    \
  dst[0][0] = LDA(d, (mh) * 4 + 0, 0); dst[0][1] = LDA(d, (mh) * 4 + 0, 1);   \
  dst[1][0] = LDA(d, (mh) * 4 + 1, 0); dst[1][1] = LDA(d, (mh) * 4 + 1, 1);   \
  dst[2][0] = LDA(d, (mh) * 4 + 2, 0); dst[2][1] = LDA(d, (mh) * 4 + 2, 1);   \
  dst[3][0] = LDA(d, (mh) * 4 + 3, 0); dst[3][1] = LDA(d, (mh) * 4 + 3, 1);

#define READ_B(d, nh, dst)                                                    \
  dst[0][0] = LDB(d, (nh) * 2 + 0, 0); dst[0][1] = LDB(d, (nh) * 2 + 0, 1);   \
  dst[1][0] = LDB(d, (nh) * 2 + 1, 0); dst[1][1] = LDB(d, (nh) * 2 + 1, 1);

#define MFMA_Q(mh, nh, ar, br)                                                \
  __builtin_amdgcn_s_setprio(1);                                              \
  _Pragma("unroll") for (int mi = 0; mi < 4; ++mi) {                          \
    _Pragma("unroll") for (int ni = 0; ni < 2; ++ni) {                        \
      acc[(mh) * 4 + mi][(nh) * 2 + ni] =                                     \
          __builtin_amdgcn_mfma_f32_16x16x32_bf16(                            \
              ar[mi][0], br[ni][0], acc[(mh) * 4 + mi][(nh) * 2 + ni], 0, 0, 0); \
      acc[(mh) * 4 + mi][(nh) * 2 + ni] =                                     \
          __builtin_amdgcn_mfma_f32_16x16x32_bf16(                            \
              ar[mi][1], br[ni][1], acc[(mh) * 4 + mi][(nh) * 2 + ni], 0, 0, 0); \
    }                                                                         \
  }                                                                           \
  __builtin_amdgcn_s_setprio(0);

  // epilogue: C/D layout col=lane&15, row=(lane>>4)*4+reg  [m89/m91 verified]
#define WRITE_C(bn_cur)                                                       \
  {                                                                           \
    const int wm = wmh * 128, wn = wn4 * 64, r0 = q * 4;                      \
    float* Cf = (float*)C + zc * zstride;                                     \
    _Pragma("unroll") for (int mf = 0; mf < 8; ++mf) {                        \
      _Pragma("unroll") for (int nf = 0; nf < 4; ++nf) {                      \
        const int col = (bn_cur) * 256 + wn + nf * 16 + lr;                   \
        const size_t rb = (size_t)(bm * 256 + wm + mf * 16 + r0);             \
        _Pragma("unroll") for (int r = 0; r < 4; ++r) {                       \
          const float v = acc[mf][nf][r];                                     \
          if (OUT_BF16) ((unsigned short*)C)[(rb + r) * N + col] = f2bf(v);   \
          else          Cf[(rb + r) * N + col] = v;                           \
        }                                                                     \
      }                                                                       \
    }                                                                         \
  }

  f32x4 acc[8][4] = {};
  bf16x8 aA[4][2], aB[4][2], bA[2][2], bB[2][2];

  // prologue: stream tile 0 -> dbuf0 {A0,A1,B0,B1}; stream tile 1 -> dbuf1 {A0,A1}
  STAGE_A(0, 0, 0); STAGE_A(1, 1, 0);
  STAGE_B(2, 0, 0); STAGE_B(3, 1, 0);
  STAGE_A(4, 0, 1); STAGE_A(5, 1, 1);
  WAITVM4();  // tile0 fully landed; tile1 A-halves still in flight
  BAR();

  int tdone = 0;
  for (int i = 0; i < TOT / 2; ++i) {
    // tile boundary: flush finished output tile, reset acc; stage pipeline
    // stays in flight (mid-epilogue overlaps next tile's staging).
    if ((2 * i & NTm1) == 0 && i != 0) {
      WRITE_C(bn0 + tdone * bn_step);
      ++tdone;
#pragma unroll
      for (int mf = 0; mf < 8; ++mf)
#pragma unroll
        for (int nf = 0; nf < 4; ++nf) acc[mf][nf] = (f32x4){0.f, 0.f, 0.f, 0.f};
    }
    const int t1 = 2 * i + 1;
    const int t2 = 2 * i + 2;
    const int t3 = 2 * i + 3;

    // ---- stream K-tile 2i from dbuf0 ----
    READ_A(0, 0, aA);
    READ_B(0, 0, bA);
    STAGE_B(6, 0, t1);
    WAITLG8();
    BAR(); WAITLG0();
    MFMA_Q(0, 0, aA, bA);
    BAR();
    READ_A(0, 1, aB);
    STAGE_B(7, 1, t1);
    BAR(); WAITLG0();
    MFMA_Q(1, 0, aB, bA);
    BAR();
    READ_B(0, 1, bB);
    STAGE_A(0, 0, t2);
    BAR(); WAITLG0();
    MFMA_Q(0, 1, aA, bB);
    BAR();
    STAGE_A(1, 1, t2);
    WAITVM4();
    BAR();
    MFMA_Q(1, 1, aB, bB);
    BAR();

    // ---- stream K-tile 2i+1 from dbuf1 ----
    READ_A(1, 0, aA);
    READ_B(1, 0, bA);
    STAGE_B(2, 0, t2);
    WAITLG8();
    BAR(); WAITLG0();
    MFMA_Q(0, 0, aA, bA);
    BAR();
    READ_A(1, 1, aB);
    STAGE_B(3, 1, t2);
    BAR(); WAITLG0();
    MFMA_Q(1, 0, aB, bA);
    BAR();
    READ_B(1, 1, bB);
    STAGE_A(4, 0, t3);
    BAR(); WAITLG0();
    MFMA_Q(0, 1, aA, bB);
    BAR();
    STAGE_A(5, 1, t3);
    WAITVM4();
    BAR();
    MFMA_Q(1, 1, aB, bB);
    BAR();
  }

  WRITE_C(bn0 + tdone * bn_step);
}

extern "C" void kernel_launch(void* const* d_in, const int* in_sizes, int n_in,
                              void* d_out, int out_size, void* d_ws, size_t ws_size,
                              hipStream_t stream) {
  const float* x  = (const float*)d_in[0];  // [4,2048,4096] = [8192,4096]
  const float* U  = (const float*)d_in[1];  // [4096,1024]
  const float* S  = (const float*)d_in[2];  // [1024]
  const float* Vh = (const float*)d_in[3];  // [1024,4096]
  float* y = (float*)d_out;                 // [8192,4096] fp32

  const int M = 8192, DIN = 4096, DOUT = 4096, R = 1024;

  char* ws = (char*)d_ws;
  unsigned short* xb = (unsigned short*)(ws);              // 67108864 B  x  bf16
  unsigned short* vs = (unsigned short*)(ws + 67108864);   //  8388608 B  S*Vh bf16
  unsigned short* ub = (unsigned short*)(ws + 75497472);   //  8388608 B  U  bf16
  unsigned short* tb = (unsigned short*)(ws + 83886080);   // 16777216 B  t  bf16
  float*          tp = (float*)(ws + 100663296);           // 67108864 B  split-K partials

  const int xN4 = M * DIN / 4, uN4 = DOUT * R / 4, vN4 = R * DIN / 4;
  prep_k<<<(xN4 + uN4 + vN4 + 255) / 256, 256, 0, stream>>>(
      x, U, Vh, S, xb, ub, vs, xN4, uN4, vN4, DIN / 4);

  if (ws_size >= 167772160) {
    // t = x @ (S*Vh)^T split-K=2: 32x4x2 = 256 blocks, fp32 partials.
    gemm256<false><<<dim3(M / 256, R / 256, 2), 512, 0, stream>>>(
        (const __bf16*)xb, (const __bf16*)vs, tp, R, DIN, DIN / 2,
        (size_t)M * R, /*CBM=*/8, /*CBN=*/4, /*CHN=*/1, /*nchunks_mn=*/4,
        /*tiles=*/1, /*bn_step=*/0);
    reduce2_bf16_k<<<(M * R / 4 + 255) / 256, 256, 0, stream>>>(
        tp, tb, M * R / 4, (size_t)M * R / 4);
  } else {
    // fallback: no split (128 blocks, half chip).
    gemm256<true><<<dim3(M / 256, R / 256, 1), 512, 0, stream>>>(
        (const __bf16*)xb, (const __bf16*)vs, tb, R, DIN, DIN, 0,
        /*CBM=*/4, /*CBN=*/4, /*CHN=*/1, /*nchunks_mn=*/8,
        /*tiles=*/1, /*bn_step=*/0);
  }

  // y = t @ U^T : [8192,4096], K=1024. Persistent 2-tile stream:
  // 32x8 = 256 blocks (1/CU, single dispatch round); block does (bm,bn0)
  // then (bm,bn0+8) sharing the A-panel. Chunks: 8 XCDs = 4(cm) x 2(cn),
  // each chunk 8bm x 4bn0.
  gemm256<false><<<dim3(M / 256, DOUT / 256 / 2, 1), 512, 0, stream>>>(
      (const __bf16*)tb, (const __bf16*)ub, y, DOUT, R, R, 0,
      /*CBM=*/8, /*CBN=*/4, /*CHN=*/2, /*nchunks_mn=*/8,
      /*tiles=*/2, /*bn_step=*/8);
}